// Round 2
// baseline (153.576 us; speedup 1.0000x reference)
//
#include <hip/hip_runtime.h>
#include <hip/hip_bf16.h>
#include <cstdint>
#include <cstddef>

#define TOK 8192
#define HID 1024
#define NE 8

typedef __bf16 bf16x4 __attribute__((ext_vector_type(4)));
typedef __bf16 bf16x8 __attribute__((ext_vector_type(8)));
typedef float floatx4 __attribute__((ext_vector_type(4)));

static __device__ __forceinline__ __bf16 f2bf(float x) {
    unsigned u = __builtin_bit_cast(unsigned, x);
    u += 0x7fffu + ((u >> 16) & 1u);   // RNE (inputs finite)
    unsigned short hs = (unsigned short)(u >> 16);
    return __builtin_bit_cast(__bf16, hs);
}

// Fused prep:
//   blocks [0, 4096):    X fp32 -> Xb bf16 (8 elems/thread); blocks [0,32) also route.
//   blocks [4096, 4608): W [E][K][N] fp32 -> Wt [E][N][K] bf16 via register 8x8
//                        micro-transpose (no LDS).
__global__ void prep_kernel(const float* __restrict__ X, const float* __restrict__ gate,
                            const float* __restrict__ W,
                            __bf16* __restrict__ Xb, __bf16* __restrict__ Wt,
                            float* __restrict__ scale, int* __restrict__ counts,
                            int* __restrict__ list) {
    const int b = blockIdx.x;
    const int t = threadIdx.x;

    if (b < 4096) {
        // ---- cvt_x ----
        size_t idx = (size_t)b * 256 + t;
        const float4 a0 = *(const float4*)(X + idx * 8);
        const float4 a1 = *(const float4*)(X + idx * 8 + 4);
        bf16x8 v;
        v[0] = f2bf(a0.x); v[1] = f2bf(a0.y); v[2] = f2bf(a0.z); v[3] = f2bf(a0.w);
        v[4] = f2bf(a1.x); v[5] = f2bf(a1.y); v[6] = f2bf(a1.z); v[7] = f2bf(a1.w);
        *(bf16x8*)(Xb + idx * 8) = v;

        // ---- route (blocks 0..31, one token per thread, LDS histogram) ----
        if (b < 32) {
            __shared__ int hcnt[NE];
            __shared__ int hbase[NE];
            if (t < NE) hcnt[t] = 0;
            __syncthreads();
            int tok = b * 256 + t;
            float g[NE];
#pragma unroll
            for (int j = 0; j < NE; j++) g[j] = gate[tok * NE + j];
            float gm = g[0]; int best = 0;
#pragma unroll
            for (int j = 1; j < NE; j++) {
                if (g[j] > gm) { gm = g[j]; best = j; }   // strict >: first-max (argmax)
            }
            float s = 0.f;
#pragma unroll
            for (int j = 0; j < NE; j++) s += __expf(g[j] - gm);
            scale[tok] = 1.0f / s;
            int lpos = atomicAdd(&hcnt[best], 1);
            __syncthreads();
            if (t < NE) hbase[t] = atomicAdd(&counts[t], hcnt[t]);
            __syncthreads();
            list[best * TOK + hbase[best] + lpos] = tok;
        }
    } else {
        // ---- cvt_wt: register micro-transpose. Block tile: k in [0,256), n in [0,64). ----
        const int bb = b - 4096;            // 0..511
        const int e  = bb >> 6;
        const int kt = (bb >> 4) & 3;
        const int nt = bb & 15;
        const int k0 = kt * 256, n0 = nt * 64;
        const int ka = t >> 3;              // 0..31: k-micro (8 rows)
        const int nb = t & 7;               // 0..7:  n-micro (8 cols)

        const float* src = W + ((size_t)e * HID + k0 + ka * 8) * HID + n0 + nb * 8;
        float rr[8][8];
#pragma unroll
        for (int i = 0; i < 8; i++) {
            float4 x = *(const float4*)(src + (size_t)i * HID);
            float4 y = *(const float4*)(src + (size_t)i * HID + 4);
            rr[i][0] = x.x; rr[i][1] = x.y; rr[i][2] = x.z; rr[i][3] = x.w;
            rr[i][4] = y.x; rr[i][5] = y.y; rr[i][6] = y.z; rr[i][7] = y.w;
        }
        __bf16* dst = Wt + ((size_t)e * HID + n0 + nb * 8) * HID + k0 + ka * 8;
#pragma unroll
        for (int j = 0; j < 8; j++) {
            bf16x8 v;
#pragma unroll
            for (int i = 0; i < 8; i++) v[i] = f2bf(rr[i][j]);
            *(bf16x8*)(dst + (size_t)j * HID) = v;
        }
    }
}

// Grouped GEMM, 64m x 64n tiles (was 128x64).
//  * WHY SMALLER: counts ~1024/expert -> the 128x64 grid had only ~1024 active
//    blocks = 4 blocks/CU of total work; measured occupancy ~2 blocks/CU avg --
//    work-starved, latency exposed. 64x64 doubles active blocks to ~2048 (8/CU
//    work, 4 resident with dbuf LDS) -- TLP does the latency hiding the 2-block
//    residency couldn't.
//  * T3-min 2-phase double-buffered pipeline kept: STAGE(next) -> MFMA(cur) ->
//    s_waitcnt vmcnt(0) -> s_barrier. Prefetch latency hides under compute.
//  * Expert-per-XCD: bid&7 == e -> XCD. Expert working set (Wt 2MB + Xb rows
//    ~2MB) ~fits the 4MB XCD L2.
//  * LDS chunk swizzle: element-chunk c of row r lives at slot c^(r&7); staging
//    fetches global chunk (p^srow) so wave-uniform global_load_lds dest lands right.
//  * Nontemporal epilogue stores keep write-once output from evicting A/B in L2.
__launch_bounds__(256)
__global__ void moe_gemm_bf16(const __bf16* __restrict__ Xb, const __bf16* __restrict__ Wt,
                              const float* __restrict__ Bias, const float* __restrict__ scale,
                              const int* __restrict__ counts, const int* __restrict__ list,
                              float* __restrict__ out) {
    const int bid = blockIdx.x;
    const int e  = bid & 7;
    const int nt = (bid >> 3) & 15;
    const int mt = bid >> 7;

    const int cnt = counts[e];
    if (mt * 64 >= cnt) return;
    const int mvalid = min(64, cnt - mt * 64);
    const int n0 = nt * 64;

    __shared__ __bf16 As[2][64 * 64];
    __shared__ __bf16 Bs[2][64 * 64];
    __shared__ int   tok[64];
    __shared__ float scl[64];

    const int tid  = threadIdx.x;
    const int lane = tid & 63;
    const int wave = tid >> 6;

    if (tid < 64) {
        int g = mt * 64 + tid;
        int tk = (g < cnt) ? list[e * TOK + g] : 0;
        tok[tid] = tk;
        scl[tid] = (g < cnt) ? scale[tk] : 0.f;
    }
    __syncthreads();

    // Staging: A rows wave*16 + i*8 + srow (i=0..1), B rows wave*16 + i*8 + srow (i=0..1).
    const int srow = lane >> 3;
    const int gchunk = ((lane & 7) ^ srow) * 8;
    const __bf16* aptr[2];
    const __bf16* bptr[2];
#pragma unroll
    for (int i = 0; i < 2; i++) {
        int r = wave * 16 + i * 8 + srow;
        aptr[i] = Xb + (size_t)tok[r] * HID + gchunk;
        bptr[i] = Wt + ((size_t)e * HID + n0 + r) * HID + gchunk;
    }

    const int ln = lane & 15;
    const int q  = lane >> 4;
    const int wm = (wave >> 1) * 32;
    const int wn = (wave & 1) * 32;
    const int rsw = ln & 7;

    floatx4 acc[2][2];
#pragma unroll
    for (int mi = 0; mi < 2; mi++)
#pragma unroll
        for (int ni = 0; ni < 2; ni++) acc[mi][ni] = (floatx4){0.f, 0.f, 0.f, 0.f};

    auto stage = [&](int b, int k0) {
#pragma unroll
        for (int i = 0; i < 2; i++) {
            __builtin_amdgcn_global_load_lds(
                (const __attribute__((address_space(1))) void*)(aptr[i] + k0),
                (__attribute__((address_space(3))) void*)(&As[b][(wave * 16 + i * 8) * 64]),
                16, 0, 0);
            __builtin_amdgcn_global_load_lds(
                (const __attribute__((address_space(1))) void*)(bptr[i] + k0),
                (__attribute__((address_space(3))) void*)(&Bs[b][(wave * 16 + i * 8) * 64]),
                16, 0, 0);
        }
    };

    auto compute = [&](int b) {
#pragma unroll
        for (int kk = 0; kk < 64; kk += 32) {
            const int cb = (kk >> 3) + q;
            const int pos = (cb ^ rsw) * 8;
            bf16x8 af[2], bfv[2];
#pragma unroll
            for (int mi = 0; mi < 2; mi++)
                af[mi] = *(const bf16x8*)(&As[b][(wm + mi * 16 + ln) * 64 + pos]);
#pragma unroll
            for (int ni = 0; ni < 2; ni++)
                bfv[ni] = *(const bf16x8*)(&Bs[b][(wn + ni * 16 + ln) * 64 + pos]);
#pragma unroll
            for (int mi = 0; mi < 2; mi++)
#pragma unroll
                for (int ni = 0; ni < 2; ni++)
                    acc[mi][ni] = __builtin_amdgcn_mfma_f32_16x16x32_bf16(
                        af[mi], bfv[ni], acc[mi][ni], 0, 0, 0);
        }
    };

    // ---- 2-phase pipeline: prologue stage, then {stage(next); compute(cur); drain; barrier} ----
    stage(0, 0);
    asm volatile("s_waitcnt vmcnt(0)" ::: "memory");
    __builtin_amdgcn_s_barrier();

    int cur = 0;
    for (int kt = 0; kt < 15; ++kt) {
        stage(cur ^ 1, (kt + 1) * 64);   // prefetch next K-tile; in flight across compute
        compute(cur);
        asm volatile("s_waitcnt vmcnt(0)" ::: "memory");  // next tile landed (had compute phase in flight)
        __builtin_amdgcn_s_barrier();
        cur ^= 1;
    }
    compute(cur);                        // last tile: nothing left to stage

    float bn[2];
#pragma unroll
    for (int ni = 0; ni < 2; ni++) bn[ni] = Bias[e * HID + n0 + wn + ni * 16 + ln];

#pragma unroll
    for (int mi = 0; mi < 2; mi++) {
#pragma unroll
        for (int r = 0; r < 4; r++) {
            int row = wm + mi * 16 + q * 4 + r;
            if (row < mvalid) {
                int t = tok[row];
                float sc = scl[row];
                size_t ob = (size_t)t * HID + n0 + wn + ln;
#pragma unroll
                for (int ni = 0; ni < 2; ni++)
                    __builtin_nontemporal_store(sc * (acc[mi][ni][r] + bn[ni]),
                                                &out[ob + ni * 16]);
            }
        }
    }
}

// ---------------- fallback (ws too small): direct fp32 reads, compile-time j ----------------
__launch_bounds__(256)
__global__ void moe_gemm_fb(const float* __restrict__ X, const float* __restrict__ W,
                            const float* __restrict__ Bias, const float* __restrict__ scale,
                            const int* __restrict__ counts, const int* __restrict__ list,
                            float* __restrict__ out) {
    const int bid = blockIdx.x;
    const int e  = bid >> 9;
    const int nt = (bid >> 6) & 7;
    const int mt = bid & 63;
    const int cnt = counts[e];
    if (mt * 128 >= cnt) return;
    const int mvalid = min(128, cnt - mt * 128);
    const int n0 = nt * 128;

    __shared__ __bf16 As[128 * 64];
    __shared__ __bf16 Bs[128 * 64];
    __shared__ int   tok[128];
    __shared__ float scl[128];

    const int tid = threadIdx.x;
    if (tid < 128) {
        int g = mt * 128 + tid;
        int tk = (g < cnt) ? list[e * TOK + g] : 0;
        tok[tid] = tk;
        scl[tid] = (g < cnt) ? scale[tk] : 0.f;
    }
    __syncthreads();

    const int c4 = tid & 15;
    const float* rp[8];
    bool rv[8];
#pragma unroll
    for (int i = 0; i < 8; i++) {
        int m = (tid >> 4) + 16 * i;
        rv[i] = (m < mvalid);
        rp[i] = X + (size_t)tok[m] * HID;
    }
    const int n4 = tid & 31;
    const int kb = tid >> 5;
    const float* wbase = W + (size_t)e * HID * HID + (size_t)(kb * 8) * HID + n0 + n4 * 4;

    const int lane = tid & 63;
    const int ln = lane & 15;
    const int q  = lane >> 4;
    const int wave = tid >> 6;
    const int wm = (wave >> 1) * 64;
    const int wn = (wave & 1) * 64;

    floatx4 acc[4][4];
#pragma unroll
    for (int mi = 0; mi < 4; mi++)
#pragma unroll
        for (int ni = 0; ni < 4; ni++) acc[mi][ni] = (floatx4){0.f, 0.f, 0.f, 0.f};

    for (int k0 = 0; k0 < HID; k0 += 64) {
#pragma unroll
        for (int i = 0; i < 8; i++) {
            int m = (tid >> 4) + 16 * i;
            float4 v = make_float4(0.f, 0.f, 0.f, 0.f);
            if (rv[i]) v = *(const float4*)(rp[i] + k0 + c4 * 4);
            bf16x4 b4;
            b4[0] = f2bf(v.x); b4[1] = f2bf(v.y); b4[2] = f2bf(v.z); b4[3] = f2bf(v.w);
            int chunk = c4 >> 1;
            int addr = m * 64 + ((chunk ^ (m & 7)) * 8) + (c4 & 1) * 4;
            *(bf16x4*)(&As[addr]) = b4;
        }
        {
            const float* wp = wbase + (size_t)k0 * HID;
            float4 rr[8];
#pragma unroll
            for (int r = 0; r < 8; r++) rr[r] = *(const float4*)(wp + (size_t)r * HID);
#pragma unroll
            for (int j = 0; j < 4; j++) {
                int n = n4 * 4 + j;
                int c = kb ^ (n & 7);
                bf16x8 pk;
                pk[0] = f2bf(j == 0 ? rr[0].x : j == 1 ? rr[0].y : j == 2 ? rr[0].z : rr[0].w);
                pk[1] = f2bf(j == 0 ? rr[1].x : j == 1 ? rr[1].y : j == 2 ? rr[1].z : rr[1].w);
                pk[2] = f2bf(j == 0 ? rr[2].x : j == 1 ? rr[2].y : j == 2 ? rr[2].z : rr[2].w);
                pk[3] = f2bf(j == 0 ? rr[3].x : j == 1 ? rr[3].y : j == 2 ? rr[3].z : rr[3].w);
                pk[4] = f2bf(j == 0 ? rr[4].x : j == 1 ? rr[4].y : j == 2 ? rr[4].z : rr[4].w);
                pk[5] = f2bf(j == 0 ? rr[5].x : j == 1 ? rr[5].y : j == 2 ? rr[5].z : rr[5].w);
                pk[6] = f2bf(j == 0 ? rr[6].x : j == 1 ? rr[6].y : j == 2 ? rr[6].z : rr[6].w);
                pk[7] = f2bf(j == 0 ? rr[7].x : j == 1 ? rr[7].y : j == 2 ? rr[7].z : rr[7].w);
                *(bf16x8*)(&Bs[n * 64 + c * 8]) = pk;
            }
        }
        __syncthreads();
#pragma unroll
        for (int kk = 0; kk < 64; kk += 32) {
            const int cbase = (kk >> 3) + q;
            bf16x8 af[4], bfv[4];
#pragma unroll
            for (int mi = 0; mi < 4; mi++) {
                int row = wm + mi * 16 + ln;
                af[mi] = *(const bf16x8*)(&As[row * 64 + ((cbase ^ (row & 7)) * 8)]);
            }
#pragma unroll
            for (int ni = 0; ni < 4; ni++) {
                int n = wn + ni * 16 + ln;
                bfv[ni] = *(const bf16x8*)(&Bs[n * 64 + ((cbase ^ (n & 7)) * 8)]);
            }
#pragma unroll
            for (int mi = 0; mi < 4; mi++)
#pragma unroll
                for (int ni = 0; ni < 4; ni++)
                    acc[mi][ni] = __builtin_amdgcn_mfma_f32_16x16x32_bf16(
                        af[mi], bfv[ni], acc[mi][ni], 0, 0, 0);
        }
        __syncthreads();
    }

    float bn[4];
#pragma unroll
    for (int ni = 0; ni < 4; ni++) bn[ni] = Bias[e * HID + n0 + wn + ni * 16 + ln];
#pragma unroll
    for (int mi = 0; mi < 4; mi++) {
#pragma unroll
        for (int r = 0; r < 4; r++) {
            int row = wm + mi * 16 + q * 4 + r;
            if (row < mvalid) {
                int t = tok[row];
                float sc = scl[row];
                size_t ob = (size_t)t * HID + n0 + wn + ln;
#pragma unroll
                for (int ni = 0; ni < 4; ni++)
                    out[ob + ni * 16] = sc * (acc[mi][ni][r] + bn[ni]);
            }
        }
    }
}

__global__ void route_fb_kernel(const float* __restrict__ gate, float* __restrict__ scale,
                                int* __restrict__ counts, int* __restrict__ list) {
    int t = blockIdx.x * blockDim.x + threadIdx.x;
    if (t >= TOK) return;
    float g[NE];
#pragma unroll
    for (int j = 0; j < NE; j++) g[j] = gate[t * NE + j];
    float gm = g[0]; int best = 0;
#pragma unroll
    for (int j = 1; j < NE; j++) {
        if (g[j] > gm) { gm = g[j]; best = j; }
    }
    float s = 0.f;
#pragma unroll
    for (int j = 0; j < NE; j++) s += __expf(g[j] - gm);
    scale[t] = 1.0f / s;
    int pos = atomicAdd(&counts[best], 1);
    list[best * TOK + pos] = t;
}

extern "C" void kernel_launch(void* const* d_in, const int* in_sizes, int n_in,
                              void* d_out, int out_size, void* d_ws, size_t ws_size,
                              hipStream_t stream) {
    const float* X    = (const float*)d_in[0];
    const float* G    = (const float*)d_in[1];
    const float* W    = (const float*)d_in[2];
    const float* Bias = (const float*)d_in[3];
    float* out = (float*)d_out;

    float* scale = (float*)d_ws;                               // 32 KB
    int* counts  = (int*)((char*)d_ws + 32768);                // 32 B (+pad)
    int* list    = (int*)((char*)d_ws + 36864);                // 256 KB -> ends 299008
    __bf16* Xb   = (__bf16*)((char*)d_ws + 299008);            // 16 MB
    __bf16* Wt   = (__bf16*)((char*)d_ws + 299008 + 16777216); // 16 MB
    const size_t need = 299008 + 2 * 16777216ULL;

    hipMemsetAsync(counts, 0, NE * sizeof(int), stream);

    if (ws_size >= need) {
        prep_kernel<<<4608, 256, 0, stream>>>(X, G, W, Xb, Wt, scale, counts, list);
        // grid: 128 mt x 16 nt x 8 e; inactive m-tiles exit immediately.
        moe_gemm_bf16<<<128 * 16 * 8, 256, 0, stream>>>(Xb, Wt, Bias, scale, counts, list, out);
    } else {
        route_fb_kernel<<<TOK / 256, 256, 0, stream>>>(G, scale, counts, list);
        moe_gemm_fb<<<NE * 64 * 8, 256, 0, stream>>>(X, W, Bias, scale, counts, list, out);
    }
}

// Round 3
// 151.125 us; speedup vs baseline: 1.0162x; 1.0162x over previous
//
#include <hip/hip_runtime.h>
#include <hip/hip_bf16.h>
#include <cstdint>
#include <cstddef>

#define TOK 8192
#define HID 1024
#define NE 8

typedef __bf16 bf16x4 __attribute__((ext_vector_type(4)));
typedef __bf16 bf16x8 __attribute__((ext_vector_type(8)));
typedef float floatx4 __attribute__((ext_vector_type(4)));

static __device__ __forceinline__ __bf16 f2bf(float x) {
    unsigned u = __builtin_bit_cast(unsigned, x);
    u += 0x7fffu + ((u >> 16) & 1u);   // RNE (inputs finite)
    unsigned short hs = (unsigned short)(u >> 16);
    return __builtin_bit_cast(__bf16, hs);
}

// Fused prep:
//   blocks [0, 4096):    X fp32 -> Xb bf16 (8 elems/thread); blocks [0,32) also route.
//   blocks [4096, 4608): W [E][K][N] fp32 -> Wt [E][N][K] bf16 via register 8x8
//                        micro-transpose (no LDS).
__global__ void prep_kernel(const float* __restrict__ X, const float* __restrict__ gate,
                            const float* __restrict__ W,
                            __bf16* __restrict__ Xb, __bf16* __restrict__ Wt,
                            float* __restrict__ scale, int* __restrict__ counts,
                            int* __restrict__ list) {
    const int b = blockIdx.x;
    const int t = threadIdx.x;

    if (b < 4096) {
        // ---- cvt_x ----
        size_t idx = (size_t)b * 256 + t;
        const float4 a0 = *(const float4*)(X + idx * 8);
        const float4 a1 = *(const float4*)(X + idx * 8 + 4);
        bf16x8 v;
        v[0] = f2bf(a0.x); v[1] = f2bf(a0.y); v[2] = f2bf(a0.z); v[3] = f2bf(a0.w);
        v[4] = f2bf(a1.x); v[5] = f2bf(a1.y); v[6] = f2bf(a1.z); v[7] = f2bf(a1.w);
        *(bf16x8*)(Xb + idx * 8) = v;

        // ---- route (blocks 0..31, one token per thread, LDS histogram) ----
        if (b < 32) {
            __shared__ int hcnt[NE];
            __shared__ int hbase[NE];
            if (t < NE) hcnt[t] = 0;
            __syncthreads();
            int tok = b * 256 + t;
            float g[NE];
#pragma unroll
            for (int j = 0; j < NE; j++) g[j] = gate[tok * NE + j];
            float gm = g[0]; int best = 0;
#pragma unroll
            for (int j = 1; j < NE; j++) {
                if (g[j] > gm) { gm = g[j]; best = j; }   // strict >: first-max (argmax)
            }
            float s = 0.f;
#pragma unroll
            for (int j = 0; j < NE; j++) s += __expf(g[j] - gm);
            scale[tok] = 1.0f / s;
            int lpos = atomicAdd(&hcnt[best], 1);
            __syncthreads();
            if (t < NE) hbase[t] = atomicAdd(&counts[t], hcnt[t]);
            __syncthreads();
            list[best * TOK + hbase[best] + lpos] = tok;
        }
    } else {
        // ---- cvt_wt: register micro-transpose. Block tile: k in [0,256), n in [0,64). ----
        const int bb = b - 4096;            // 0..511
        const int e  = bb >> 6;
        const int kt = (bb >> 4) & 3;
        const int nt = bb & 15;
        const int k0 = kt * 256, n0 = nt * 64;
        const int ka = t >> 3;              // 0..31: k-micro (8 rows)
        const int nb = t & 7;               // 0..7:  n-micro (8 cols)

        const float* src = W + ((size_t)e * HID + k0 + ka * 8) * HID + n0 + nb * 8;
        float rr[8][8];
#pragma unroll
        for (int i = 0; i < 8; i++) {
            float4 x = *(const float4*)(src + (size_t)i * HID);
            float4 y = *(const float4*)(src + (size_t)i * HID + 4);
            rr[i][0] = x.x; rr[i][1] = x.y; rr[i][2] = x.z; rr[i][3] = x.w;
            rr[i][4] = y.x; rr[i][5] = y.y; rr[i][6] = y.z; rr[i][7] = y.w;
        }
        __bf16* dst = Wt + ((size_t)e * HID + n0 + nb * 8) * HID + k0 + ka * 8;
#pragma unroll
        for (int j = 0; j < 8; j++) {
            bf16x8 v;
#pragma unroll
            for (int i = 0; i < 8; i++) v[i] = f2bf(rr[i][j]);
            *(bf16x8*)(dst + (size_t)j * HID) = v;
        }
    }
}

// Grouped GEMM, 64m x 64n tiles, DEPTH-2 PREFETCH (T3+T4 counted-vmcnt).
//  * WHY: rounds 0-2 all landed at 42-45 us with MfmaUtil ~15% regardless of
//    tile size / dbuf / occupancy. Model: per-K-tile time ~825cy = compute
//    (~300cy) + exposed load latency (~500cy). The 1-deep pipe's vmcnt(0)
//    waited on loads issued only ONE compute-phase ago. Fix = loads stay in
//    flight across TWO phases: triple-buffered LDS, stage(t+2) while
//    computing t, s_waitcnt vmcnt(8) (= 2 tiles x 4 loads/wave still
//    outstanding) -- never drain to 0 in the main loop (m218: counted-vs-
//    drain0 was the whole gain of the 8-phase schedule).
//  * Two raw s_barriers per tile (WAR before stage; visibility before
//    compute), no drain attached. Loop fully unrolled -> buffer indices are
//    compile-time.
//  * T5 s_setprio(1) around MFMA cluster: waves now sit in different phases
//    (stage vs compute) -- the regime where m218b measured +21%.
//  * Expert-per-XCD: bid&7 == e -> XCD. LDS chunk swizzle as before.
__launch_bounds__(256)
__global__ void moe_gemm_bf16(const __bf16* __restrict__ Xb, const __bf16* __restrict__ Wt,
                              const float* __restrict__ Bias, const float* __restrict__ scale,
                              const int* __restrict__ counts, const int* __restrict__ list,
                              float* __restrict__ out) {
    const int bid = blockIdx.x;
    const int e  = bid & 7;
    const int nt = (bid >> 3) & 15;
    const int mt = bid >> 7;

    const int cnt = counts[e];
    if (mt * 64 >= cnt) return;
    const int mvalid = min(64, cnt - mt * 64);
    const int n0 = nt * 64;

    __shared__ __bf16 As[3][64 * 64];
    __shared__ __bf16 Bs[3][64 * 64];
    __shared__ int   tok[64];
    __shared__ float scl[64];

    const int tid  = threadIdx.x;
    const int lane = tid & 63;
    const int wave = tid >> 6;

    if (tid < 64) {
        int g = mt * 64 + tid;
        int tk = (g < cnt) ? list[e * TOK + g] : 0;
        tok[tid] = tk;
        scl[tid] = (g < cnt) ? scale[tk] : 0.f;
    }
    __syncthreads();

    // Staging: A rows wave*16 + i*8 + srow (i=0..1), B rows wave*16 + i*8 + srow (i=0..1).
    const int srow = lane >> 3;
    const int gchunk = ((lane & 7) ^ srow) * 8;
    const __bf16* aptr[2];
    const __bf16* bptr[2];
#pragma unroll
    for (int i = 0; i < 2; i++) {
        int r = wave * 16 + i * 8 + srow;
        aptr[i] = Xb + (size_t)tok[r] * HID + gchunk;
        bptr[i] = Wt + ((size_t)e * HID + n0 + r) * HID + gchunk;
    }

    const int ln = lane & 15;
    const int q  = lane >> 4;
    const int wm = (wave >> 1) * 32;
    const int wn = (wave & 1) * 32;
    const int rsw = ln & 7;

    floatx4 acc[2][2];
#pragma unroll
    for (int mi = 0; mi < 2; mi++)
#pragma unroll
        for (int ni = 0; ni < 2; ni++) acc[mi][ni] = (floatx4){0.f, 0.f, 0.f, 0.f};

    auto stage = [&](int b, int k0) {
#pragma unroll
        for (int i = 0; i < 2; i++) {
            __builtin_amdgcn_global_load_lds(
                (const __attribute__((address_space(1))) void*)(aptr[i] + k0),
                (__attribute__((address_space(3))) void*)(&As[b][(wave * 16 + i * 8) * 64]),
                16, 0, 0);
            __builtin_amdgcn_global_load_lds(
                (const __attribute__((address_space(1))) void*)(bptr[i] + k0),
                (__attribute__((address_space(3))) void*)(&Bs[b][(wave * 16 + i * 8) * 64]),
                16, 0, 0);
        }
    };

    auto compute = [&](int b) {
        __builtin_amdgcn_s_setprio(1);
#pragma unroll
        for (int kk = 0; kk < 64; kk += 32) {
            const int cb = (kk >> 3) + q;
            const int pos = (cb ^ rsw) * 8;
            bf16x8 af[2], bfv[2];
#pragma unroll
            for (int mi = 0; mi < 2; mi++)
                af[mi] = *(const bf16x8*)(&As[b][(wm + mi * 16 + ln) * 64 + pos]);
#pragma unroll
            for (int ni = 0; ni < 2; ni++)
                bfv[ni] = *(const bf16x8*)(&Bs[b][(wn + ni * 16 + ln) * 64 + pos]);
#pragma unroll
            for (int mi = 0; mi < 2; mi++)
#pragma unroll
                for (int ni = 0; ni < 2; ni++)
                    acc[mi][ni] = __builtin_amdgcn_mfma_f32_16x16x32_bf16(
                        af[mi], bfv[ni], acc[mi][ni], 0, 0, 0);
        }
        __builtin_amdgcn_s_setprio(0);
    };

    // ---- depth-2 pipeline over 16 K-tiles, 3 LDS buffers ----
    // prologue: tiles 0 and 1 in flight (8 outstanding VMEM/wave)
    stage(0, 0);
    stage(1, 64);

#pragma unroll
    for (int t = 0; t < 14; ++t) {
        __builtin_amdgcn_s_barrier();                      // WAR: all done with buf[(t+2)%3]'s old tile
        stage((t + 2) % 3, (t + 2) * 64);                  // 12 outstanding
        asm volatile("s_waitcnt vmcnt(8)" ::: "memory");   // tile t's 4 loads (oldest) done
        __builtin_amdgcn_s_barrier();                      // tile t visible from every wave
        compute(t % 3);
    }
    // t = 14: tiles 14,15 outstanding (8); wait tile 14 -> vmcnt(4)
    asm volatile("s_waitcnt vmcnt(4)" ::: "memory");
    __builtin_amdgcn_s_barrier();
    compute(14 % 3);
    // t = 15: drain
    asm volatile("s_waitcnt vmcnt(0)" ::: "memory");
    __builtin_amdgcn_s_barrier();
    compute(15 % 3);

    float bn[2];
#pragma unroll
    for (int ni = 0; ni < 2; ni++) bn[ni] = Bias[e * HID + n0 + wn + ni * 16 + ln];

#pragma unroll
    for (int mi = 0; mi < 2; mi++) {
#pragma unroll
        for (int r = 0; r < 4; r++) {
            int row = wm + mi * 16 + q * 4 + r;
            if (row < mvalid) {
                int t = tok[row];
                float sc = scl[row];
                size_t ob = (size_t)t * HID + n0 + wn + ln;
#pragma unroll
                for (int ni = 0; ni < 2; ni++)
                    __builtin_nontemporal_store(sc * (acc[mi][ni][r] + bn[ni]),
                                                &out[ob + ni * 16]);
            }
        }
    }
}

// ---------------- fallback (ws too small): direct fp32 reads, compile-time j ----------------
__launch_bounds__(256)
__global__ void moe_gemm_fb(const float* __restrict__ X, const float* __restrict__ W,
                            const float* __restrict__ Bias, const float* __restrict__ scale,
                            const int* __restrict__ counts, const int* __restrict__ list,
                            float* __restrict__ out) {
    const int bid = blockIdx.x;
    const int e  = bid >> 9;
    const int nt = (bid >> 6) & 7;
    const int mt = bid & 63;
    const int cnt = counts[e];
    if (mt * 128 >= cnt) return;
    const int mvalid = min(128, cnt - mt * 128);
    const int n0 = nt * 128;

    __shared__ __bf16 As[128 * 64];
    __shared__ __bf16 Bs[128 * 64];
    __shared__ int   tok[128];
    __shared__ float scl[128];

    const int tid = threadIdx.x;
    if (tid < 128) {
        int g = mt * 128 + tid;
        int tk = (g < cnt) ? list[e * TOK + g] : 0;
        tok[tid] = tk;
        scl[tid] = (g < cnt) ? scale[tk] : 0.f;
    }
    __syncthreads();

    const int c4 = tid & 15;
    const float* rp[8];
    bool rv[8];
#pragma unroll
    for (int i = 0; i < 8; i++) {
        int m = (tid >> 4) + 16 * i;
        rv[i] = (m < mvalid);
        rp[i] = X + (size_t)tok[m] * HID;
    }
    const int n4 = tid & 31;
    const int kb = tid >> 5;
    const float* wbase = W + (size_t)e * HID * HID + (size_t)(kb * 8) * HID + n0 + n4 * 4;

    const int lane = tid & 63;
    const int ln = lane & 15;
    const int q  = lane >> 4;
    const int wave = tid >> 6;
    const int wm = (wave >> 1) * 64;
    const int wn = (wave & 1) * 64;

    floatx4 acc[4][4];
#pragma unroll
    for (int mi = 0; mi < 4; mi++)
#pragma unroll
        for (int ni = 0; ni < 4; ni++) acc[mi][ni] = (floatx4){0.f, 0.f, 0.f, 0.f};

    for (int k0 = 0; k0 < HID; k0 += 64) {
#pragma unroll
        for (int i = 0; i < 8; i++) {
            int m = (tid >> 4) + 16 * i;
            float4 v = make_float4(0.f, 0.f, 0.f, 0.f);
            if (rv[i]) v = *(const float4*)(rp[i] + k0 + c4 * 4);
            bf16x4 b4;
            b4[0] = f2bf(v.x); b4[1] = f2bf(v.y); b4[2] = f2bf(v.z); b4[3] = f2bf(v.w);
            int chunk = c4 >> 1;
            int addr = m * 64 + ((chunk ^ (m & 7)) * 8) + (c4 & 1) * 4;
            *(bf16x4*)(&As[addr]) = b4;
        }
        {
            const float* wp = wbase + (size_t)k0 * HID;
            float4 rr[8];
#pragma unroll
            for (int r = 0; r < 8; r++) rr[r] = *(const float4*)(wp + (size_t)r * HID);
#pragma unroll
            for (int j = 0; j < 4; j++) {
                int n = n4 * 4 + j;
                int c = kb ^ (n & 7);
                bf16x8 pk;
                pk[0] = f2bf(j == 0 ? rr[0].x : j == 1 ? rr[0].y : j == 2 ? rr[0].z : rr[0].w);
                pk[1] = f2bf(j == 0 ? rr[1].x : j == 1 ? rr[1].y : j == 2 ? rr[1].z : rr[1].w);
                pk[2] = f2bf(j == 0 ? rr[2].x : j == 1 ? rr[2].y : j == 2 ? rr[2].z : rr[2].w);
                pk[3] = f2bf(j == 0 ? rr[3].x : j == 1 ? rr[3].y : j == 2 ? rr[3].z : rr[3].w);
                pk[4] = f2bf(j == 0 ? rr[4].x : j == 1 ? rr[4].y : j == 2 ? rr[4].z : rr[4].w);
                pk[5] = f2bf(j == 0 ? rr[5].x : j == 1 ? rr[5].y : j == 2 ? rr[5].z : rr[5].w);
                pk[6] = f2bf(j == 0 ? rr[6].x : j == 1 ? rr[6].y : j == 2 ? rr[6].z : rr[6].w);
                pk[7] = f2bf(j == 0 ? rr[7].x : j == 1 ? rr[7].y : j == 2 ? rr[7].z : rr[7].w);
                *(bf16x8*)(&Bs[n * 64 + c * 8]) = pk;
            }
        }
        __syncthreads();
#pragma unroll
        for (int kk = 0; kk < 64; kk += 32) {
            const int cbase = (kk >> 3) + q;
            bf16x8 af[4], bfv[4];
#pragma unroll
            for (int mi = 0; mi < 4; mi++) {
                int row = wm + mi * 16 + ln;
                af[mi] = *(const bf16x8*)(&As[row * 64 + ((cbase ^ (row & 7)) * 8)]);
            }
#pragma unroll
            for (int ni = 0; ni < 4; ni++) {
                int n = wn + ni * 16 + ln;
                bfv[ni] = *(const bf16x8*)(&Bs[n * 64 + ((cbase ^ (n & 7)) * 8)]);
            }
#pragma unroll
            for (int mi = 0; mi < 4; mi++)
#pragma unroll
                for (int ni = 0; ni < 4; ni++)
                    acc[mi][ni] = __builtin_amdgcn_mfma_f32_16x16x32_bf16(
                        af[mi], bfv[ni], acc[mi][ni], 0, 0, 0);
        }
        __syncthreads();
    }

    float bn[4];
#pragma unroll
    for (int ni = 0; ni < 4; ni++) bn[ni] = Bias[e * HID + n0 + wn + ni * 16 + ln];
#pragma unroll
    for (int mi = 0; mi < 4; mi++) {
#pragma unroll
        for (int r = 0; r < 4; r++) {
            int row = wm + mi * 16 + q * 4 + r;
            if (row < mvalid) {
                int t = tok[row];
                float sc = scl[row];
                size_t ob = (size_t)t * HID + n0 + wn + ln;
#pragma unroll
                for (int ni = 0; ni < 4; ni++)
                    out[ob + ni * 16] = sc * (acc[mi][ni][r] + bn[ni]);
            }
        }
    }
}

__global__ void route_fb_kernel(const float* __restrict__ gate, float* __restrict__ scale,
                                int* __restrict__ counts, int* __restrict__ list) {
    int t = blockIdx.x * blockDim.x + threadIdx.x;
    if (t >= TOK) return;
    float g[NE];
#pragma unroll
    for (int j = 0; j < NE; j++) g[j] = gate[t * NE + j];
    float gm = g[0]; int best = 0;
#pragma unroll
    for (int j = 1; j < NE; j++) {
        if (g[j] > gm) { gm = g[j]; best = j; }
    }
    float s = 0.f;
#pragma unroll
    for (int j = 0; j < NE; j++) s += __expf(g[j] - gm);
    scale[t] = 1.0f / s;
    int pos = atomicAdd(&counts[best], 1);
    list[best * TOK + pos] = t;
}

extern "C" void kernel_launch(void* const* d_in, const int* in_sizes, int n_in,
                              void* d_out, int out_size, void* d_ws, size_t ws_size,
                              hipStream_t stream) {
    const float* X    = (const float*)d_in[0];
    const float* G    = (const float*)d_in[1];
    const float* W    = (const float*)d_in[2];
    const float* Bias = (const float*)d_in[3];
    float* out = (float*)d_out;

    float* scale = (float*)d_ws;                               // 32 KB
    int* counts  = (int*)((char*)d_ws + 32768);                // 32 B (+pad)
    int* list    = (int*)((char*)d_ws + 36864);                // 256 KB -> ends 299008
    __bf16* Xb   = (__bf16*)((char*)d_ws + 299008);            // 16 MB
    __bf16* Wt   = (__bf16*)((char*)d_ws + 299008 + 16777216); // 16 MB
    const size_t need = 299008 + 2 * 16777216ULL;

    hipMemsetAsync(counts, 0, NE * sizeof(int), stream);

    if (ws_size >= need) {
        prep_kernel<<<4608, 256, 0, stream>>>(X, G, W, Xb, Wt, scale, counts, list);
        // grid: 128 mt x 16 nt x 8 e; inactive m-tiles exit immediately.
        moe_gemm_bf16<<<128 * 16 * 8, 256, 0, stream>>>(Xb, Wt, Bias, scale, counts, list, out);
    } else {
        route_fb_kernel<<<TOK / 256, 256, 0, stream>>>(G, scale, counts, list);
        moe_gemm_fb<<<NE * 64 * 8, 256, 0, stream>>>(X, W, Bias, scale, counts, list, out);
    }
}

// Round 5
// 141.544 us; speedup vs baseline: 1.0850x; 1.0677x over previous
//
#include <hip/hip_runtime.h>
#include <hip/hip_bf16.h>
#include <cstdint>
#include <cstddef>

#define TOK 8192
#define HID 1024
#define NE 8

typedef __bf16 bf16x4 __attribute__((ext_vector_type(4)));
typedef __bf16 bf16x8 __attribute__((ext_vector_type(8)));
typedef float floatx4 __attribute__((ext_vector_type(4)));

static __device__ __forceinline__ __bf16 f2bf(float x) {
    unsigned u = __builtin_bit_cast(unsigned, x);
    u += 0x7fffu + ((u >> 16) & 1u);   // RNE (inputs finite)
    unsigned short hs = (unsigned short)(u >> 16);
    return __builtin_bit_cast(__bf16, hs);
}

// Fused prep. Block order matters:
//   blocks [0, 1024):        W [E][K][N] fp32 -> Wt [E][N][K] bf16, 128k x 64n tiles,
//                            8x4 register micro-transpose. DISPATCHED FIRST: these are
//                            the latency-bound blocks (serial dependent-load chains);
//                            putting them first overlaps them with the streaming X part
//                            instead of running them as a starved 2-block/CU tail
//                            (old layout: 512 blocks AFTER 4096 X blocks).
//   blocks [1024, 5120):     X fp32 -> Xb bf16 (8 elems/thread); first 32 also route.
__global__ void prep_kernel(const float* __restrict__ X, const float* __restrict__ gate,
                            const float* __restrict__ W,
                            __bf16* __restrict__ Xb, __bf16* __restrict__ Wt,
                            float* __restrict__ scale, int* __restrict__ counts,
                            int* __restrict__ list) {
    const int b = blockIdx.x;
    const int t = threadIdx.x;

    if (b < 1024) {
        // ---- cvt_wt: 128k x 64n tile per block; thread owns 8k x 4n micro-tile. ----
        const int e  = b >> 7;              // 8 experts x 128 blocks
        const int rem = b & 127;
        const int kt = rem >> 4;            // 0..7  (8 x 128 = 1024 k)
        const int nt = rem & 15;            // 0..15 (16 x 64 = 1024 n)
        const int k0 = kt * 128, n0 = nt * 64;
        const int cg = t & 15;              // col group: 4 n-cols
        const int rg = t >> 4;              // row group: 8 k-rows

        const float* src = W + ((size_t)e * HID + k0 + rg * 8) * HID + n0 + cg * 4;
        float rr[8][4];
#pragma unroll
        for (int i = 0; i < 8; i++) {
            float4 x = *(const float4*)(src + (size_t)i * HID);
            rr[i][0] = x.x; rr[i][1] = x.y; rr[i][2] = x.z; rr[i][3] = x.w;
        }
        // write: row n = n0+cg*4+j, k chunk k0+rg*8 (16B). Per wave, fixed j: lanes
        // (rg 0..3, cg 0..15) -> 16 segments of 64B contiguous (full lines).
        __bf16* dst = Wt + ((size_t)e * HID + n0 + cg * 4) * HID + k0 + rg * 8;
#pragma unroll
        for (int j = 0; j < 4; j++) {
            bf16x8 v;
#pragma unroll
            for (int i = 0; i < 8; i++) v[i] = f2bf(rr[i][j]);
            *(bf16x8*)(dst + (size_t)j * HID) = v;
        }
    } else {
        // ---- cvt_x ----
        const int bb = b - 1024;            // 0..4095
        size_t idx = (size_t)bb * 256 + t;
        const float4 a0 = *(const float4*)(X + idx * 8);
        const float4 a1 = *(const float4*)(X + idx * 8 + 4);
        bf16x8 v;
        v[0] = f2bf(a0.x); v[1] = f2bf(a0.y); v[2] = f2bf(a0.z); v[3] = f2bf(a0.w);
        v[4] = f2bf(a1.x); v[5] = f2bf(a1.y); v[6] = f2bf(a1.z); v[7] = f2bf(a1.w);
        *(bf16x8*)(Xb + idx * 8) = v;

        // ---- route (first 32 X-blocks, one token per thread, LDS histogram) ----
        if (bb < 32) {
            __shared__ int hcnt[NE];
            __shared__ int hbase[NE];
            if (t < NE) hcnt[t] = 0;
            __syncthreads();
            int tok = bb * 256 + t;
            float g[NE];
#pragma unroll
            for (int j = 0; j < NE; j++) g[j] = gate[tok * NE + j];
            float gm = g[0]; int best = 0;
#pragma unroll
            for (int j = 1; j < NE; j++) {
                if (g[j] > gm) { gm = g[j]; best = j; }   // strict >: first-max (argmax)
            }
            float s = 0.f;
#pragma unroll
            for (int j = 0; j < NE; j++) s += __expf(g[j] - gm);
            scale[tok] = 1.0f / s;
            int lpos = atomicAdd(&hcnt[best], 1);
            __syncthreads();
            if (t < NE) hbase[t] = atomicAdd(&counts[t], hcnt[t]);
            __syncthreads();
            list[best * TOK + hbase[best] + lpos] = tok;
        }
    }
}

// Grouped GEMM, 64m x 64n tiles, DEPTH-2 PREFETCH (T3+T4 counted-vmcnt).
// (unchanged from round 3 -- this version dropped GEMM below the 41us fill floor)
//  * triple-buffered LDS, stage(t+2) while computing t, s_waitcnt vmcnt(8) --
//    loads get TWO compute phases in flight; never drain to 0 in the main loop.
//  * Two raw s_barriers per tile (WAR before stage; visibility before compute).
//  * T5 s_setprio(1) around MFMA cluster.
//  * Expert-per-XCD: bid&7 == e -> XCD. LDS chunk swizzle c^(r&7).
__launch_bounds__(256)
__global__ void moe_gemm_bf16(const __bf16* __restrict__ Xb, const __bf16* __restrict__ Wt,
                              const float* __restrict__ Bias, const float* __restrict__ scale,
                              const int* __restrict__ counts, const int* __restrict__ list,
                              float* __restrict__ out) {
    const int bid = blockIdx.x;
    const int e  = bid & 7;
    const int nt = (bid >> 3) & 15;
    const int mt = bid >> 7;

    const int cnt = counts[e];
    if (mt * 64 >= cnt) return;
    const int mvalid = min(64, cnt - mt * 64);
    const int n0 = nt * 64;

    __shared__ __bf16 As[3][64 * 64];
    __shared__ __bf16 Bs[3][64 * 64];
    __shared__ int   tok[64];
    __shared__ float scl[64];

    const int tid  = threadIdx.x;
    const int lane = tid & 63;
    const int wave = tid >> 6;

    if (tid < 64) {
        int g = mt * 64 + tid;
        int tk = (g < cnt) ? list[e * TOK + g] : 0;
        tok[tid] = tk;
        scl[tid] = (g < cnt) ? scale[tk] : 0.f;
    }
    __syncthreads();

    // Staging: A rows wave*16 + i*8 + srow (i=0..1), B rows wave*16 + i*8 + srow (i=0..1).
    const int srow = lane >> 3;
    const int gchunk = ((lane & 7) ^ srow) * 8;
    const __bf16* aptr[2];
    const __bf16* bptr[2];
#pragma unroll
    for (int i = 0; i < 2; i++) {
        int r = wave * 16 + i * 8 + srow;
        aptr[i] = Xb + (size_t)tok[r] * HID + gchunk;
        bptr[i] = Wt + ((size_t)e * HID + n0 + r) * HID + gchunk;
    }

    const int ln = lane & 15;
    const int q  = lane >> 4;
    const int wm = (wave >> 1) * 32;
    const int wn = (wave & 1) * 32;
    const int rsw = ln & 7;

    floatx4 acc[2][2];
#pragma unroll
    for (int mi = 0; mi < 2; mi++)
#pragma unroll
        for (int ni = 0; ni < 2; ni++) acc[mi][ni] = (floatx4){0.f, 0.f, 0.f, 0.f};

    auto stage = [&](int b, int k0) {
#pragma unroll
        for (int i = 0; i < 2; i++) {
            __builtin_amdgcn_global_load_lds(
                (const __attribute__((address_space(1))) void*)(aptr[i] + k0),
                (__attribute__((address_space(3))) void*)(&As[b][(wave * 16 + i * 8) * 64]),
                16, 0, 0);
            __builtin_amdgcn_global_load_lds(
                (const __attribute__((address_space(1))) void*)(bptr[i] + k0),
                (__attribute__((address_space(3))) void*)(&Bs[b][(wave * 16 + i * 8) * 64]),
                16, 0, 0);
        }
    };

    auto compute = [&](int b) {
        __builtin_amdgcn_s_setprio(1);
#pragma unroll
        for (int kk = 0; kk < 64; kk += 32) {
            const int cb = (kk >> 3) + q;
            const int pos = (cb ^ rsw) * 8;
            bf16x8 af[2], bfv[2];
#pragma unroll
            for (int mi = 0; mi < 2; mi++)
                af[mi] = *(const bf16x8*)(&As[b][(wm + mi * 16 + ln) * 64 + pos]);
#pragma unroll
            for (int ni = 0; ni < 2; ni++)
                bfv[ni] = *(const bf16x8*)(&Bs[b][(wn + ni * 16 + ln) * 64 + pos]);
#pragma unroll
            for (int mi = 0; mi < 2; mi++)
#pragma unroll
                for (int ni = 0; ni < 2; ni++)
                    acc[mi][ni] = __builtin_amdgcn_mfma_f32_16x16x32_bf16(
                        af[mi], bfv[ni], acc[mi][ni], 0, 0, 0);
        }
        __builtin_amdgcn_s_setprio(0);
    };

    // ---- depth-2 pipeline over 16 K-tiles, 3 LDS buffers ----
    stage(0, 0);
    stage(1, 64);

#pragma unroll
    for (int t = 0; t < 14; ++t) {
        __builtin_amdgcn_s_barrier();                      // WAR: all done with buf[(t+2)%3]'s old tile
        stage((t + 2) % 3, (t + 2) * 64);                  // 12 outstanding
        asm volatile("s_waitcnt vmcnt(8)" ::: "memory");   // tile t's 4 loads (oldest) done
        __builtin_amdgcn_s_barrier();                      // tile t visible from every wave
        compute(t % 3);
    }
    asm volatile("s_waitcnt vmcnt(4)" ::: "memory");
    __builtin_amdgcn_s_barrier();
    compute(14 % 3);
    asm volatile("s_waitcnt vmcnt(0)" ::: "memory");
    __builtin_amdgcn_s_barrier();
    compute(15 % 3);

    float bn[2];
#pragma unroll
    for (int ni = 0; ni < 2; ni++) bn[ni] = Bias[e * HID + n0 + wn + ni * 16 + ln];

#pragma unroll
    for (int mi = 0; mi < 2; mi++) {
#pragma unroll
        for (int r = 0; r < 4; r++) {
            int row = wm + mi * 16 + q * 4 + r;
            if (row < mvalid) {
                int t = tok[row];
                float sc = scl[row];
                size_t ob = (size_t)t * HID + n0 + wn + ln;
#pragma unroll
                for (int ni = 0; ni < 2; ni++)
                    __builtin_nontemporal_store(sc * (acc[mi][ni][r] + bn[ni]),
                                                &out[ob + ni * 16]);
            }
        }
    }
}

// ---------------- fallback (ws too small): direct fp32 reads, compile-time j ----------------
__launch_bounds__(256)
__global__ void moe_gemm_fb(const float* __restrict__ X, const float* __restrict__ W,
                            const float* __restrict__ Bias, const float* __restrict__ scale,
                            const int* __restrict__ counts, const int* __restrict__ list,
                            float* __restrict__ out) {
    const int bid = blockIdx.x;
    const int e  = bid >> 9;
    const int nt = (bid >> 6) & 7;
    const int mt = bid & 63;
    const int cnt = counts[e];
    if (mt * 128 >= cnt) return;
    const int mvalid = min(128, cnt - mt * 128);
    const int n0 = nt * 128;

    __shared__ __bf16 As[128 * 64];
    __shared__ __bf16 Bs[128 * 64];
    __shared__ int   tok[128];
    __shared__ float scl[128];

    const int tid = threadIdx.x;
    if (tid < 128) {
        int g = mt * 128 + tid;
        int tk = (g < cnt) ? list[e * TOK + g] : 0;
        tok[tid] = tk;
        scl[tid] = (g < cnt) ? scale[tk] : 0.f;
    }
    __syncthreads();

    const int c4 = tid & 15;
    const float* rp[8];
    bool rv[8];
#pragma unroll
    for (int i = 0; i < 8; i++) {
        int m = (tid >> 4) + 16 * i;
        rv[i] = (m < mvalid);
        rp[i] = X + (size_t)tok[m] * HID;
    }
    const int n4 = tid & 31;
    const int kb = tid >> 5;
    const float* wbase = W + (size_t)e * HID * HID + (size_t)(kb * 8) * HID + n0 + n4 * 4;

    const int lane = tid & 63;
    const int ln = lane & 15;
    const int q  = lane >> 4;
    const int wave = tid >> 6;
    const int wm = (wave >> 1) * 64;
    const int wn = (wave & 1) * 64;

    floatx4 acc[4][4];
#pragma unroll
    for (int mi = 0; mi < 4; mi++)
#pragma unroll
        for (int ni = 0; ni < 4; ni++) acc[mi][ni] = (floatx4){0.f, 0.f, 0.f, 0.f};

    for (int k0 = 0; k0 < HID; k0 += 64) {
#pragma unroll
        for (int i = 0; i < 8; i++) {
            int m = (tid >> 4) + 16 * i;
            float4 v = make_float4(0.f, 0.f, 0.f, 0.f);
            if (rv[i]) v = *(const float4*)(rp[i] + k0 + c4 * 4);
            bf16x4 b4;
            b4[0] = f2bf(v.x); b4[1] = f2bf(v.y); b4[2] = f2bf(v.z); b4[3] = f2bf(v.w);
            int chunk = c4 >> 1;
            int addr = m * 64 + ((chunk ^ (m & 7)) * 8) + (c4 & 1) * 4;
            *(bf16x4*)(&As[addr]) = b4;
        }
        {
            const float* wp = wbase + (size_t)k0 * HID;
            float4 rr[8];
#pragma unroll
            for (int r = 0; r < 8; r++) rr[r] = *(const float4*)(wp + (size_t)r * HID);
#pragma unroll
            for (int j = 0; j < 4; j++) {
                int n = n4 * 4 + j;
                int c = kb ^ (n & 7);
                bf16x8 pk;
                pk[0] = f2bf(j == 0 ? rr[0].x : j == 1 ? rr[0].y : j == 2 ? rr[0].z : rr[0].w);
                pk[1] = f2bf(j == 0 ? rr[1].x : j == 1 ? rr[1].y : j == 2 ? rr[1].z : rr[1].w);
                pk[2] = f2bf(j == 0 ? rr[2].x : j == 1 ? rr[2].y : j == 2 ? rr[2].z : rr[2].w);
                pk[3] = f2bf(j == 0 ? rr[3].x : j == 1 ? rr[3].y : j == 2 ? rr[3].z : rr[3].w);
                pk[4] = f2bf(j == 0 ? rr[4].x : j == 1 ? rr[4].y : j == 2 ? rr[4].z : rr[4].w);
                pk[5] = f2bf(j == 0 ? rr[5].x : j == 1 ? rr[5].y : j == 2 ? rr[5].z : rr[5].w);
                pk[6] = f2bf(j == 0 ? rr[6].x : j == 1 ? rr[6].y : j == 2 ? rr[6].z : rr[6].w);
                pk[7] = f2bf(j == 0 ? rr[7].x : j == 1 ? rr[7].y : j == 2 ? rr[7].z : rr[7].w);
                *(bf16x8*)(&Bs[n * 64 + c * 8]) = pk;
            }
        }
        __syncthreads();
#pragma unroll
        for (int kk = 0; kk < 64; kk += 32) {
            const int cbase = (kk >> 3) + q;
            bf16x8 af[4], bfv[4];
#pragma unroll
            for (int mi = 0; mi < 4; mi++) {
                int row = wm + mi * 16 + ln;
                af[mi] = *(const bf16x8*)(&As[row * 64 + ((cbase ^ (row & 7)) * 8)]);
            }
#pragma unroll
            for (int ni = 0; ni < 4; ni++) {
                int n = wn + ni * 16 + ln;
                bfv[ni] = *(const bf16x8*)(&Bs[n * 64 + ((cbase ^ (n & 7)) * 8)]);
            }
#pragma unroll
            for (int mi = 0; mi < 4; mi++)
#pragma unroll
                for (int ni = 0; ni < 4; ni++)
                    acc[mi][ni] = __builtin_amdgcn_mfma_f32_16x16x32_bf16(
                        af[mi], bfv[ni], acc[mi][ni], 0, 0, 0);
        }
        __syncthreads();
    }

    float bn[4];
#pragma unroll
    for (int ni = 0; ni < 4; ni++) bn[ni] = Bias[e * HID + n0 + wn + ni * 16 + ln];
#pragma unroll
    for (int mi = 0; mi < 4; mi++) {
#pragma unroll
        for (int r = 0; r < 4; r++) {
            int row = wm + mi * 16 + q * 4 + r;
            if (row < mvalid) {
                int t = tok[row];
                float sc = scl[row];
                size_t ob = (size_t)t * HID + n0 + wn + ln;
#pragma unroll
                for (int ni = 0; ni < 4; ni++)
                    out[ob + ni * 16] = sc * (acc[mi][ni][r] + bn[ni]);
            }
        }
    }
}

__global__ void route_fb_kernel(const float* __restrict__ gate, float* __restrict__ scale,
                                int* __restrict__ counts, int* __restrict__ list) {
    int t = blockIdx.x * blockDim.x + threadIdx.x;
    if (t >= TOK) return;
    float g[NE];
#pragma unroll
    for (int j = 0; j < NE; j++) g[j] = gate[t * NE + j];
    float gm = g[0]; int best = 0;
#pragma unroll
    for (int j = 1; j < NE; j++) {
        if (g[j] > gm) { gm = g[j]; best = j; }
    }
    float s = 0.f;
#pragma unroll
    for (int j = 0; j < NE; j++) s += __expf(g[j] - gm);
    scale[t] = 1.0f / s;
    int pos = atomicAdd(&counts[best], 1);
    list[best * TOK + pos] = t;
}

extern "C" void kernel_launch(void* const* d_in, const int* in_sizes, int n_in,
                              void* d_out, int out_size, void* d_ws, size_t ws_size,
                              hipStream_t stream) {
    const float* X    = (const float*)d_in[0];
    const float* G    = (const float*)d_in[1];
    const float* W    = (const float*)d_in[2];
    const float* Bias = (const float*)d_in[3];
    float* out = (float*)d_out;

    float* scale = (float*)d_ws;                               // 32 KB
    int* counts  = (int*)((char*)d_ws + 32768);                // 32 B (+pad)
    int* list    = (int*)((char*)d_ws + 36864);                // 256 KB -> ends 299008
    __bf16* Xb   = (__bf16*)((char*)d_ws + 299008);            // 16 MB
    __bf16* Wt   = (__bf16*)((char*)d_ws + 299008 + 16777216); // 16 MB
    const size_t need = 299008 + 2 * 16777216ULL;

    hipMemsetAsync(counts, 0, NE * sizeof(int), stream);

    if (ws_size >= need) {
        // 1024 W-transpose blocks FIRST (latency-bound, overlap with X streaming),
        // then 4096 X-convert blocks (first 32 of which also route).
        prep_kernel<<<5120, 256, 0, stream>>>(X, G, W, Xb, Wt, scale, counts, list);
        // grid: 128 mt x 16 nt x 8 e; inactive m-tiles exit immediately.
        moe_gemm_bf16<<<128 * 16 * 8, 256, 0, stream>>>(Xb, Wt, Bias, scale, counts, list, out);
    } else {
        route_fb_kernel<<<TOK / 256, 256, 0, stream>>>(G, scale, counts, list);
        moe_gemm_fb<<<NE * 64 * 8, 256, 0, stream>>>(X, W, Bias, scale, counts, list, out);
    }
}